// Round 6
// baseline (426.960 us; speedup 1.0000x reference)
//
#include <hip/hip_runtime.h>
#include <hip/hip_bf16.h>
#include <stdint.h>

// ---------------------------------------------------------------------------
// BondPoolingLayer: out[e] = MLP(cat(h[src],h[dst])) + MLP(cat(h[dst],h[src]))
// MLP: 256 ->(W1,b1,relu) 128 ->(W2,b2,relu) 128 ->(W3,b3) 2
//
// P[n,0:128] = h[n] @ W1_top ; P[n,128:256] = h[n] @ W1_bot + b1   (bf16)
//   fwd layer1 preact = P[s,0:128] + P[d,128:256]
//   rev layer1 preact = P[d,0:128] + P[s,128:256]
//
// R6 = R5 math (proven absmax 0.03125) + persistent blocks + SW pipeline:
//  - weights staged into LDS ONCE per block (amortized over 3-7 tiles)
//  - grid-stride tile loop; next tile's global loads issued while current
//    tile's MFMA body runs (cross-iteration prefetch, regs double-buffered)
//  - node_proj: grid 512 (2 blocks/CU via 64KB LDS), ~3 tiles/block
//  - edge_mlp: grid 256 (~6.7 tiles/block), 2-deep index pipeline
// ---------------------------------------------------------------------------

typedef __attribute__((ext_vector_type(8))) short bf16x8;
typedef __attribute__((ext_vector_type(4))) float f32x4;

__device__ __forceinline__ float bf2f(unsigned u16) {
    union { unsigned u; float f; } v; v.u = u16 << 16;
    return v.f;
}
__device__ __forceinline__ unsigned short f2bf(float f) {
    union { float f; unsigned u; } v; v.f = f;
    unsigned u = v.u;
    unsigned r = u + 0x7FFFu + ((u >> 16) & 1u);   // RNE
    return (unsigned short)(r >> 16);
}

// LDS swizzle: tiles are [rows][128 bf16], chunk = 8 bf16 (16B), 16 chunks/row.
__device__ __forceinline__ int swz(int f, int c) {
    return f * 128 + ((c ^ (f & 7)) << 3);
}

// two float4 (8 consecutive fp32) -> bf16x8 fragment (packed RNE cvt)
__device__ __forceinline__ bf16x8 cvt8r(float4 x, float4 y) {
    union { bf16x8 v; __hip_bfloat162 h[4]; } R;
    R.h[0] = __float22bfloat162_rn(float2{x.x, x.y});
    R.h[1] = __float22bfloat162_rn(float2{x.z, x.w});
    R.h[2] = __float22bfloat162_rn(float2{y.x, y.y});
    R.h[3] = __float22bfloat162_rn(float2{y.z, y.w});
    return R.v;
}

// elementwise relu(a+b) over 8 bf16 pairs (fp32 math), repacked to bf16x8
__device__ __forceinline__ bf16x8 addrelu8(uint4 a, uint4 b) {
    union { uint4 v; unsigned u[4]; } A, B;
    A.v = a; B.v = b;
    union { bf16x8 v; __hip_bfloat162 h[4]; } R;
#pragma unroll
    for (int i = 0; i < 4; ++i) {
        float a0 = bf2f(A.u[i] & 0xFFFFu), a1 = bf2f(A.u[i] >> 16);
        float b0 = bf2f(B.u[i] & 0xFFFFu), b1 = bf2f(B.u[i] >> 16);
        R.h[i] = __float22bfloat162_rn(float2{fmaxf(a0 + b0, 0.f),
                                              fmaxf(a1 + b1, 0.f)});
    }
    return R.v;
}

#define MFMA(a, b, c) __builtin_amdgcn_mfma_f32_16x16x32_bf16((a), (b), (c), 0, 0, 0)

// ---------------------------------------------------------------------------
// Kernel 0: weight prep (bf16 transposes, plain row-major).
// W1t[j][k] (j in [0,256), k in [0,128)) = W1[k][j] (j<128) | W1[k+128][j-128]
// W2t[n][k] = W2[k][n]
// ---------------------------------------------------------------------------
__global__ void prep_weights(const float* __restrict__ W1,
                             const float* __restrict__ W2,
                             unsigned short* __restrict__ W1t,
                             unsigned short* __restrict__ W2t) {
    int idx = blockIdx.x * 256 + threadIdx.x;
    if (idx < 256 * 128) {
        int j = idx >> 7, k = idx & 127;
        float v = (j < 128) ? W1[k * 128 + j] : W1[(k + 128) * 128 + (j - 128)];
        W1t[idx] = f2bf(v);
    } else {
        int i2 = idx - 256 * 128;
        if (i2 < 128 * 128) {
            int n = i2 >> 7, k = i2 & 127;
            W2t[i2] = f2bf(W2[k * 128 + n]);
        }
    }
}

// ---------------------------------------------------------------------------
// Kernel A: node projection, persistent. Block = 512 thr; tile = 128 nodes;
// wave = 16 nodes x 256 features. W1s (64KB) staged once per block.
// ---------------------------------------------------------------------------
__global__ __launch_bounds__(512, 2) void node_proj(
    const float* __restrict__ h, const unsigned short* __restrict__ W1t,
    const float* __restrict__ b1, unsigned short* __restrict__ P,
    int nodes, int ntiles) {
    __shared__ unsigned short W1s[256 * 128];

    int t = threadIdx.x;
    int lane = t & 63;
    int wv = t >> 6;
    int ml = lane & 15, quad = lane >> 4;

    // stage W1s once: thread t -> row t>>1, 8 chunks (swizzled)
    {
        int r = t >> 1, half = t & 1;
        const uint4* src = (const uint4*)(W1t + (size_t)r * 128 + half * 64);
#pragma unroll
        for (int i = 0; i < 8; ++i)
            *(uint4*)(W1s + swz(r, half * 8 + i)) = src[i];
    }

    // prefetch first tile's h (fp32, 8x16B per lane)
    int tile = blockIdx.x;
    float4 hreg[8];
    if (tile < ntiles) {
        int nd = tile * 128 + wv * 16 + ml;
        if (nd >= nodes) nd = nodes - 1;
        const float4* hp = (const float4*)(h + (size_t)nd * 128);
#pragma unroll
        for (int kk = 0; kk < 4; ++kk) {
            hreg[2 * kk]     = hp[kk * 8 + quad * 2];
            hreg[2 * kk + 1] = hp[kk * 8 + quad * 2 + 1];
        }
    }

    __syncthreads();   // W1s ready

    for (; tile < ntiles; tile += gridDim.x) {
        // consume hreg -> bf16 fragments
        bf16x8 bfrag[4];
#pragma unroll
        for (int kk = 0; kk < 4; ++kk)
            bfrag[kk] = cvt8r(hreg[2 * kk], hreg[2 * kk + 1]);

        int node = tile * 128 + wv * 16 + ml;   // this tile's node (for store)

        // issue NEXT tile's loads (overlaps the MFMA body below)
        int ntile = tile + gridDim.x;
        if (ntile < ntiles) {
            int nd = ntile * 128 + wv * 16 + ml;
            if (nd >= nodes) nd = nodes - 1;
            const float4* hp = (const float4*)(h + (size_t)nd * 128);
#pragma unroll
            for (int kk = 0; kk < 4; ++kk) {
                hreg[2 * kk]     = hp[kk * 8 + quad * 2];
                hreg[2 * kk + 1] = hp[kk * 8 + quad * 2 + 1];
            }
        }

        f32x4 acc[16] = {};
#pragma unroll
        for (int kk = 0; kk < 4; ++kk) {
#pragma unroll
            for (int ct = 0; ct < 16; ++ct) {
                bf16x8 afrag = *(const bf16x8*)(W1s + swz(ct * 16 + ml, kk * 4 + quad));
                acc[ct] = MFMA(afrag, bfrag[kk], acc[ct]);
            }
        }

        // epilogue: lane ml owns node; rows (features) = ct*16 + quad*4 + reg
        if (node < nodes) {
            unsigned short* prow = P + (size_t)node * 256;
#pragma unroll
            for (int ct = 0; ct < 16; ++ct) {
                int fbase = ct * 16 + quad * 4;
                float v0 = acc[ct][0], v1 = acc[ct][1];
                float v2 = acc[ct][2], v3 = acc[ct][3];
                if (fbase >= 128) {
                    float4 bv = *(const float4*)(b1 + (fbase - 128));
                    v0 += bv.x; v1 += bv.y; v2 += bv.z; v3 += bv.w;
                }
                union { uint2 u; __hip_bfloat162 h2[2]; } o;
                o.h2[0] = __float22bfloat162_rn(float2{v0, v1});
                o.h2[1] = __float22bfloat162_rn(float2{v2, v3});
                *(uint2*)(prow + fbase) = o.u;
            }
        }
    }
}

// ---------------------------------------------------------------------------
// Kernel B: per-edge MLP, persistent. Block = 512 thr; tile = 128 edges;
// wave = 16 edges x {fwd,rev}. W2s (32KB) staged once per block.
// Pipeline: idx for tile t+1 in flight one full iteration before its gathers.
// ---------------------------------------------------------------------------
__global__ __launch_bounds__(512, 2) void edge_mlp(
    const unsigned short* __restrict__ P, const int* __restrict__ src,
    const int* __restrict__ dst, const unsigned short* __restrict__ W2t,
    const float* __restrict__ b2, const float* __restrict__ W3,
    const float* __restrict__ b3, float* __restrict__ out, int E, int etiles) {
    __shared__ unsigned short W2s[128 * 128];

    int t = threadIdx.x;
    int lane = t & 63;
    int wv = t >> 6;
    int ml = lane & 15, quad = lane >> 4;

    // stage W2s once: thread t -> row t>>2, 4 chunks (swizzled)
    {
        int f = t >> 2, q4 = t & 3;
        const uint4* s = (const uint4*)(W2t + (size_t)f * 128 + q4 * 32);
#pragma unroll
        for (int i = 0; i < 4; ++i)
            *(uint4*)(W2s + swz(f, q4 * 4 + i)) = s[i];
    }

    // loop-invariant epilogue constants (depend only on ml)
    float w30[8], w31[8], b2v[8];
#pragma unroll
    for (int ct = 0; ct < 8; ++ct) {
        int c = ct * 16 + ml;
        w30[ct] = W3[c * 2 + 0];
        w31[ct] = W3[c * 2 + 1];
        b2v[ct] = b2[c];
    }
    float bb0 = 2.f * b3[0], bb1 = 2.f * b3[1];

    int tile = blockIdx.x;

    // prime: idx + gathers for first tile, idx for second
    int si = 0, di = 0, si2 = 0, di2 = 0;
    uint4 g[4][4];
    if (tile < etiles) {
        int e0 = tile * 128 + wv * 16 + ml;
        int ec = (e0 < E) ? e0 : (E - 1);
        si = src[ec]; di = dst[ec];
        const unsigned short* Ps = P + (size_t)si * 256;
        const unsigned short* Pd = P + (size_t)di * 256;
#pragma unroll
        for (int kk = 0; kk < 4; ++kk) {
            int ko = kk * 32 + quad * 8;
            g[kk][0] = *(const uint4*)(Ps + ko);
            g[kk][1] = *(const uint4*)(Ps + 128 + ko);
            g[kk][2] = *(const uint4*)(Pd + ko);
            g[kk][3] = *(const uint4*)(Pd + 128 + ko);
        }
        int t2 = tile + gridDim.x;
        if (t2 < etiles) {
            int e2 = t2 * 128 + wv * 16 + ml;
            int ec2 = (e2 < E) ? e2 : (E - 1);
            si2 = src[ec2]; di2 = dst[ec2];
        }
    }

    __syncthreads();   // W2s ready

    for (; tile < etiles; tile += gridDim.x) {
        // consume gathers -> A fragments (frees g)
        bf16x8 afw[4], arv[4];
#pragma unroll
        for (int kk = 0; kk < 4; ++kk) {
            afw[kk] = addrelu8(g[kk][0], g[kk][3]);   // relu(P[s,k]+P[d,128+k])
            arv[kk] = addrelu8(g[kk][2], g[kk][1]);   // relu(P[d,k]+P[s,128+k])
        }

        int ebase = tile * 128 + wv * 16;   // this tile's edges (for store)

        // issue NEXT tile's gathers (idx already in flight) + idx for tile+2
        int ntile = tile + gridDim.x;
        if (ntile < etiles) {
            const unsigned short* Ps = P + (size_t)si2 * 256;
            const unsigned short* Pd = P + (size_t)di2 * 256;
#pragma unroll
            for (int kk = 0; kk < 4; ++kk) {
                int ko = kk * 32 + quad * 8;
                g[kk][0] = *(const uint4*)(Ps + ko);
                g[kk][1] = *(const uint4*)(Ps + 128 + ko);
                g[kk][2] = *(const uint4*)(Pd + ko);
                g[kk][3] = *(const uint4*)(Pd + 128 + ko);
            }
            int t2 = ntile + gridDim.x;
            if (t2 < etiles) {
                int e2 = t2 * 128 + wv * 16 + ml;
                int ec2 = (e2 < E) ? e2 : (E - 1);
                si2 = src[ec2]; di2 = dst[ec2];
            }
        }

        f32x4 acc[2][8] = {};
#pragma unroll
        for (int kk = 0; kk < 4; ++kk) {
#pragma unroll
            for (int ct = 0; ct < 8; ++ct) {
                bf16x8 bfrag = *(const bf16x8*)(W2s + swz(ct * 16 + ml, kk * 4 + quad));
                acc[0][ct] = MFMA(afw[kk], bfrag, acc[0][ct]);
                acc[1][ct] = MFMA(arv[kk], bfrag, acc[1][ct]);
            }
        }

        // epilogue: +b2, relu, dot W3 columns, butterfly over 16 feature lanes
        float p0[2][4], p1[2][4];
#pragma unroll
        for (int rt = 0; rt < 2; ++rt)
#pragma unroll
            for (int reg = 0; reg < 4; ++reg) { p0[rt][reg] = 0.f; p1[rt][reg] = 0.f; }
#pragma unroll
        for (int rt = 0; rt < 2; ++rt)
#pragma unroll
            for (int ct = 0; ct < 8; ++ct)
#pragma unroll
                for (int reg = 0; reg < 4; ++reg) {
                    float h2 = fmaxf(acc[rt][ct][reg] + b2v[ct], 0.f);
                    p0[rt][reg] += h2 * w30[ct];
                    p1[rt][reg] += h2 * w31[ct];
                }
#pragma unroll
        for (int m = 1; m < 16; m <<= 1) {
#pragma unroll
            for (int rt = 0; rt < 2; ++rt)
#pragma unroll
                for (int reg = 0; reg < 4; ++reg) {
                    p0[rt][reg] += __shfl_xor(p0[rt][reg], m);
                    p1[rt][reg] += __shfl_xor(p1[rt][reg], m);
                }
        }

        if (ml < 2) {
#pragma unroll
            for (int reg = 0; reg < 4; ++reg) {
                int ee = ebase + quad * 4 + reg;
                if (ee < E) {
                    float v = (ml == 0) ? (p0[0][reg] + p0[1][reg] + bb0)
                                        : (p1[0][reg] + p1[1][reg] + bb1);
                    out[(size_t)ee * 2 + ml] = v;
                }
            }
        }
    }
}

// ---------------------------------------------------------------------------
extern "C" void kernel_launch(void* const* d_in, const int* in_sizes, int n_in,
                              void* d_out, int out_size, void* d_ws, size_t ws_size,
                              hipStream_t stream) {
    (void)n_in; (void)out_size; (void)ws_size;
    const float* h  = (const float*)d_in[0];
    const int*   sr = (const int*)d_in[1];
    const int*   ds = (const int*)d_in[2];
    const float* W1 = (const float*)d_in[3];
    const float* b1 = (const float*)d_in[4];
    const float* W2 = (const float*)d_in[5];
    const float* b2 = (const float*)d_in[6];
    const float* W3 = (const float*)d_in[7];
    const float* b3 = (const float*)d_in[8];
    float* out = (float*)d_out;

    int nodes = in_sizes[0] / 128;
    int E = in_sizes[1];

    unsigned short* W1t = (unsigned short*)d_ws;          // 256*128
    unsigned short* W2t = W1t + 256 * 128;                // 128*128
    unsigned short* P   = W2t + 128 * 128;                // nodes*256

    prep_weights<<<(256 * 128 + 128 * 128 + 255) / 256, 256, 0, stream>>>(W1, W2, W1t, W2t);

    int ntiles = (nodes + 127) / 128;
    int ngrid = (ntiles < 512) ? ntiles : 512;
    node_proj<<<ngrid, 512, 0, stream>>>(h, W1t, b1, P, nodes, ntiles);

    int etiles = (E + 127) / 128;
    int egrid = (etiles < 256) ? etiles : 256;
    edge_mlp<<<egrid, 512, 0, stream>>>(P, sr, ds, W2t, b2, W3, b3, out, E, etiles);
}

// Round 7
// 247.142 us; speedup vs baseline: 1.7276x; 1.7276x over previous
//
#include <hip/hip_runtime.h>
#include <hip/hip_bf16.h>
#include <stdint.h>

// ---------------------------------------------------------------------------
// BondPoolingLayer: out[e] = MLP(cat(h[src],h[dst])) + MLP(cat(h[dst],h[src]))
// MLP: 256 ->(W1,b1,relu) 128 ->(W2,b2,relu) 128 ->(W3,b3) 2
//
// P[n,0:128] = h[n] @ W1_top ; P[n,128:256] = h[n] @ W1_bot + b1   (bf16)
//   fwd layer1 preact = P[s,0:128] + P[d,128:256]
//   rev layer1 preact = P[d,0:128] + P[s,128:256]
//
// R7 = R5 math (proven absmax 0.03125) + two fixes from R6's traffic evidence:
//  1. node_proj epilogue: wave-private LDS bounce (reuses dead W1s region) ->
//     P stores are 1KB-contiguous global_store_dwordx4 instead of 256
//     scattered 32B sectors per wave (store-path was the ~80us limiter).
//  2. Weight transposes folded into the consumers (stage LDS straight from
//     fp32 W1/W2 globals, L2-hot broadcast reads) -> 2 dispatches, no W1t/W2t.
// ---------------------------------------------------------------------------

typedef __attribute__((ext_vector_type(8))) short bf16x8;
typedef __attribute__((ext_vector_type(4))) float f32x4;

__device__ __forceinline__ float bf2f(unsigned u16) {
    union { unsigned u; float f; } v; v.u = u16 << 16;
    return v.f;
}

// LDS swizzle for weight tiles [rows][128 bf16], chunk = 8 bf16 (16B).
__device__ __forceinline__ int swz(int f, int c) {
    return f * 128 + ((c ^ (f & 7)) << 3);
}

// elementwise relu(a+b) over 8 bf16 pairs (fp32 math), repacked to bf16x8
__device__ __forceinline__ bf16x8 addrelu8(uint4 a, uint4 b) {
    union { uint4 v; unsigned u[4]; } A, B;
    A.v = a; B.v = b;
    union { bf16x8 v; __hip_bfloat162 h[4]; } R;
#pragma unroll
    for (int i = 0; i < 4; ++i) {
        float a0 = bf2f(A.u[i] & 0xFFFFu), a1 = bf2f(A.u[i] >> 16);
        float b0 = bf2f(B.u[i] & 0xFFFFu), b1 = bf2f(B.u[i] >> 16);
        R.h[i] = __float22bfloat162_rn(float2{fmaxf(a0 + b0, 0.f),
                                              fmaxf(a1 + b1, 0.f)});
    }
    return R.v;
}

// pack 8 fp32 (RNE) -> uint4 of 8 bf16
__device__ __forceinline__ uint4 pack8(const float* v) {
    union { uint4 u; __hip_bfloat162 h[4]; } R;
#pragma unroll
    for (int i = 0; i < 4; ++i)
        R.h[i] = __float22bfloat162_rn(float2{v[2 * i], v[2 * i + 1]});
    return R.u;
}

#define MFMA(a, b, c) __builtin_amdgcn_mfma_f32_16x16x32_bf16((a), (b), (c), 0, 0, 0)

// ---------------------------------------------------------------------------
// Kernel A: node projection. Block = 512 thr = 8 waves = 128 nodes (1 tile).
// Wave = 16 nodes x 256 features. W1 staged fp32->bf16 LDS once per block.
// Epilogue: LDS bounce -> fully coalesced 1KB P stores.
// ---------------------------------------------------------------------------
__global__ __launch_bounds__(512, 2) void node_proj(
    const float* __restrict__ h, const float* __restrict__ W1,
    const float* __restrict__ b1, unsigned short* __restrict__ P, int nodes) {
    __shared__ unsigned short W1s[256 * 128];   // 64 KB; reused as bounce buf

    int t = threadIdx.x;
    int lane = t & 63;
    int wv = t >> 6;
    int ml = lane & 15, quad = lane >> 4;

    // ---- stage W1cat^T into LDS directly from fp32 W1 (RNE to bf16).
    // W1cat[k][j] = W1[k][j] (j<128) | W1[k+128][j-128].  Row j, chunks of 8 k.
    {
        int j = t >> 1, half = t & 1;
        const float* col = (j < 128) ? (W1 + j) : (W1 + 128 * 128 + (j - 128));
#pragma unroll
        for (int ci = 0; ci < 8; ++ci) {
            int c = half * 8 + ci;             // chunk: k in [c*8, c*8+8)
            float v[8];
#pragma unroll
            for (int l = 0; l < 8; ++l)
                v[l] = col[(c * 8 + l) * 128];
            *(uint4*)(W1s + swz(j, c)) = pack8(v);
        }
    }

    // ---- prefetch this wave's 16 h rows (fp32) while W1 stages
    int tile = blockIdx.x;
    int node = tile * 128 + wv * 16 + ml;
    int nodeL = (node < nodes) ? node : (nodes - 1);
    const float4* hp = (const float4*)(h + (size_t)nodeL * 128);
    float4 hreg[8];
#pragma unroll
    for (int kk = 0; kk < 4; ++kk) {
        hreg[2 * kk]     = hp[kk * 8 + quad * 2];
        hreg[2 * kk + 1] = hp[kk * 8 + quad * 2 + 1];
    }

    __syncthreads();   // W1s ready

    // cvt h -> bf16 B fragments
    bf16x8 bfrag[4];
#pragma unroll
    for (int kk = 0; kk < 4; ++kk) {
        union { bf16x8 v; __hip_bfloat162 hh[4]; } R;
        float4 x = hreg[2 * kk], y = hreg[2 * kk + 1];
        R.hh[0] = __float22bfloat162_rn(float2{x.x, x.y});
        R.hh[1] = __float22bfloat162_rn(float2{x.z, x.w});
        R.hh[2] = __float22bfloat162_rn(float2{y.x, y.y});
        R.hh[3] = __float22bfloat162_rn(float2{y.z, y.w});
        bfrag[kk] = R.v;
    }

    f32x4 acc[16] = {};
#pragma unroll
    for (int kk = 0; kk < 4; ++kk) {
#pragma unroll
        for (int ct = 0; ct < 16; ++ct) {
            bf16x8 afrag = *(const bf16x8*)(W1s + swz(ct * 16 + ml, kk * 4 + quad));
            acc[ct] = MFMA(afrag, bfrag[kk], acc[ct]);
        }
    }

    __syncthreads();   // all waves done reading W1s -> safe to reuse as bounce

    // ---- bounce: wave-private 8KB slice; chunk-XOR swizzle (chunk = 16B)
    unsigned* slice = (unsigned*)W1s + wv * 2048;   // 2048 dwords = 8 KB
#pragma unroll
    for (int ct = 0; ct < 16; ++ct) {
        int fbase = ct * 16 + quad * 4;
        float v0 = acc[ct][0], v1 = acc[ct][1];
        float v2 = acc[ct][2], v3 = acc[ct][3];
        if (fbase >= 128) {
            float4 bv = *(const float4*)(b1 + (fbase - 128));
            v0 += bv.x; v1 += bv.y; v2 += bv.z; v3 += bv.w;
        }
        union { uint2 u; __hip_bfloat162 h2[2]; } o;
        o.h2[0] = __float22bfloat162_rn(float2{v0, v1});
        o.h2[1] = __float22bfloat162_rn(float2{v2, v3});
        int c = ct * 2 + (quad >> 1);                     // 16B chunk in row
        int idx = ml * 128 + ((c ^ ml) << 2) + ((quad & 1) << 1);
        *(uint2*)(slice + idx) = o.u;
    }
    // wave-internal read-back (compiler inserts lgkmcnt wait), coalesced store
#pragma unroll
    for (int i = 0; i < 8; ++i) {
        int n = i * 2 + (lane >> 5);      // node index within wave's 16
        int cr = lane & 31;               // 16B chunk within 512B row
        uint4 val = *(const uint4*)(slice + n * 128 + ((cr ^ n) << 2));
        int gnode = tile * 128 + wv * 16 + n;
        if (gnode < nodes)
            *(uint4*)((unsigned*)(P + (size_t)gnode * 256) + cr * 4) = val;
    }
}

// ---------------------------------------------------------------------------
// Kernel B: per-edge MLP. Block = 512 thr = 8 waves = 128 edges.
// Wave = 16 edges x {fwd,rev}. W2 staged fp32->bf16 LDS once per block.
// ---------------------------------------------------------------------------
__global__ __launch_bounds__(512, 2) void edge_mlp(
    const unsigned short* __restrict__ P, const int* __restrict__ src,
    const int* __restrict__ dst, const float* __restrict__ W2,
    const float* __restrict__ b2, const float* __restrict__ W3,
    const float* __restrict__ b3, float* __restrict__ out, int E) {
    __shared__ unsigned short W2s[128 * 128];

    int t = threadIdx.x;
    int lane = t & 63;
    int wv = t >> 6;
    int ml = lane & 15, quad = lane >> 4;

    // ---- stage W2^T into LDS directly from fp32 W2: row f, chunks of 8 k
    {
        int f = t >> 2, q4 = t & 3;
        const float* col = W2 + f;
#pragma unroll
        for (int ci = 0; ci < 4; ++ci) {
            int c = q4 * 4 + ci;
            float v[8];
#pragma unroll
            for (int l = 0; l < 8; ++l)
                v[l] = col[(c * 8 + l) * 128];
            *(uint4*)(W2s + swz(f, c)) = pack8(v);
        }
    }

    // ---- prefetch all P gathers for this lane's edge
    int e = blockIdx.x * 128 + wv * 16 + ml;
    int ec = (e < E) ? e : (E - 1);
    int si = src[ec], di = dst[ec];
    const unsigned short* Ps = P + (size_t)si * 256;
    const unsigned short* Pd = P + (size_t)di * 256;

    uint4 g[4][4];   // [kk][s_lo, s_hi, d_lo, d_hi]
#pragma unroll
    for (int kk = 0; kk < 4; ++kk) {
        int ko = kk * 32 + quad * 8;
        g[kk][0] = *(const uint4*)(Ps + ko);
        g[kk][1] = *(const uint4*)(Ps + 128 + ko);
        g[kk][2] = *(const uint4*)(Pd + ko);
        g[kk][3] = *(const uint4*)(Pd + 128 + ko);
    }

    __syncthreads();   // W2s ready

    f32x4 acc[2][8] = {};
#pragma unroll
    for (int kk = 0; kk < 4; ++kk) {
        bf16x8 afw = addrelu8(g[kk][0], g[kk][3]);   // fwd: relu(P[s,k]+P[d,128+k])
        bf16x8 arv = addrelu8(g[kk][2], g[kk][1]);   // rev: relu(P[d,k]+P[s,128+k])
#pragma unroll
        for (int ct = 0; ct < 8; ++ct) {
            bf16x8 bfrag = *(const bf16x8*)(W2s + swz(ct * 16 + ml, kk * 4 + quad));
            acc[0][ct] = MFMA(afw, bfrag, acc[0][ct]);
            acc[1][ct] = MFMA(arv, bfrag, acc[1][ct]);
        }
    }

    // ---- epilogue: +b2, relu, dot W3 columns, butterfly over 16 feature lanes
    float w30[8], w31[8], b2v[8];
#pragma unroll
    for (int ct = 0; ct < 8; ++ct) {
        int c = ct * 16 + ml;
        w30[ct] = W3[c * 2 + 0];
        w31[ct] = W3[c * 2 + 1];
        b2v[ct] = b2[c];
    }
    float p0[2][4], p1[2][4];
#pragma unroll
    for (int rt = 0; rt < 2; ++rt)
#pragma unroll
        for (int reg = 0; reg < 4; ++reg) { p0[rt][reg] = 0.f; p1[rt][reg] = 0.f; }
#pragma unroll
    for (int rt = 0; rt < 2; ++rt)
#pragma unroll
        for (int ct = 0; ct < 8; ++ct)
#pragma unroll
            for (int reg = 0; reg < 4; ++reg) {
                float h2 = fmaxf(acc[rt][ct][reg] + b2v[ct], 0.f);
                p0[rt][reg] += h2 * w30[ct];
                p1[rt][reg] += h2 * w31[ct];
            }
#pragma unroll
    for (int m = 1; m < 16; m <<= 1) {
#pragma unroll
        for (int rt = 0; rt < 2; ++rt)
#pragma unroll
            for (int reg = 0; reg < 4; ++reg) {
                p0[rt][reg] += __shfl_xor(p0[rt][reg], m);
                p1[rt][reg] += __shfl_xor(p1[rt][reg], m);
            }
    }

    if (ml < 2) {
        float bb = 2.f * b3[ml];
#pragma unroll
        for (int reg = 0; reg < 4; ++reg) {
            int ee = blockIdx.x * 128 + wv * 16 + quad * 4 + reg;
            if (ee < E) {
                float v = (ml == 0) ? (p0[0][reg] + p0[1][reg])
                                    : (p1[0][reg] + p1[1][reg]);
                out[(size_t)ee * 2 + ml] = v + bb;
            }
        }
    }
}

// ---------------------------------------------------------------------------
extern "C" void kernel_launch(void* const* d_in, const int* in_sizes, int n_in,
                              void* d_out, int out_size, void* d_ws, size_t ws_size,
                              hipStream_t stream) {
    (void)n_in; (void)out_size; (void)ws_size;
    const float* h  = (const float*)d_in[0];
    const int*   sr = (const int*)d_in[1];
    const int*   ds = (const int*)d_in[2];
    const float* W1 = (const float*)d_in[3];
    const float* b1 = (const float*)d_in[4];
    const float* W2 = (const float*)d_in[5];
    const float* b2 = (const float*)d_in[6];
    const float* W3 = (const float*)d_in[7];
    const float* b3 = (const float*)d_in[8];
    float* out = (float*)d_out;

    int nodes = in_sizes[0] / 128;
    int E = in_sizes[1];

    unsigned short* P = (unsigned short*)d_ws;   // nodes*256 bf16

    int ntiles = (nodes + 127) / 128;
    node_proj<<<ntiles, 512, 0, stream>>>(h, W1, b1, P, nodes);

    int etiles = (E + 127) / 128;
    edge_mlp<<<etiles, 512, 0, stream>>>(P, sr, ds, W2, b2, W3, b3, out, E);
}